// Round 11
// baseline (14199.719 us; speedup 1.0000x reference)
//
#include <hip/hip_runtime.h>

#define NNODE 101
#define DIM   128
#define NHEAD 8
#define NSTEP 150
#define BTOT  2048
#define ENCP  132          // padded enc row stride in LDS

// packed-weight ws layout (floats)
#define OFF_FCP   0
#define OFF_FC1P  16384
#define OFF_MWP   32768
#define OFF_MVP   49152
#define OFF_FP    65536
#define OFF_MKP   81920
#define OFF_FCC   98304
#define NORM_PROB 0.08838834764831845f

// R16: R15's K-split REVERTED (it fired the correctness gate: absmax=100,
// argmax flip — greedy rollout tolerates NO reassociation). Bit-exact
// parallelism instead: 512 threads (8 waves) per 1-element block, same
// ~70KB LDS -> still 2 blocks/CU, 16 waves/CU. Phases with independent
// per-output chains spread thinner (chains untouched, just re-owned):
//   PH3: thread=(h=tl&7, nb=tl>>3) — 1 head (was pair), 256 fma/thread
//   PH4: 8 waves = 8 heads (was 2/wave)
//   PH5: thread=(h=tl>>6, j2) — 1 head (was pair), 202 fma/thread
//   PH7: thread=(qd, n=tl>>2) — 1 node (was 2)
// 128-chain matvecs unchanged: PH1 fc q0/fc1 q1; PH2 q0; PH5b q1; PH6 q0.
// pl ping-pong kept (bit-exact, -1 barrier): init->pl[0]; step s reads
// pl[s&1], writes pl[s&1^1]; PH2 reads pl[s&1^1].
struct __align__(16) BS {
  float enc[NNODE * ENCP];              // 53,328 B
  float pl[2][DIM];                     // ping-pong
  float dec[DIM], q[DIM], attn[DIM], op[DIM];
  float U[1888];                        // QK/ZR: h*132+i ; CMP: 1056+h*104+n
  float sc[1212];                       // SC: n*12+h ; SRED: n*12+k
  float mask[NNODE], mask1[NNODE], dem[NNODE];
  float cap, lp;
  int   idx;
};                                      // ~70.0 KB -> 2 blocks/CU

#define EL(n,i)     S.enc[(n)*ENCP + (i)]
#define QK(h,i)     S.U[(h)*132 + (i)]
#define ZR(h,i)     S.U[(h)*132 + (i)]
#define CMP(h,n)    S.U[1056 + (h)*104 + (n)]
#define SC(n,h)     S.sc[(n)*12 + (h)]
#define SRED(n,k)   S.sc[(n)*12 + (k)]

// Pack all weights as float4 panels: P[i4*128 + j] = {wT[i4*4+0][j], .., wT[i4*4+3][j]}
__global__ void prep_weights(const float* __restrict__ fc_w,
                             const float* __restrict__ fc1_w,
                             const float* __restrict__ mw_w,
                             const float* __restrict__ mv_w,
                             const float* __restrict__ mfc_w,
                             const float* __restrict__ pk_w,
                             const float* __restrict__ mk_w,
                             float* __restrict__ ws) {
  int x = blockIdx.x * 256 + threadIdx.x;
  if (x < 4096) {                      // fcP
    int i4 = x >> 7, j = x & 127;
    float4 v = make_float4(fc_w[j * 129 + i4 * 4 + 0], fc_w[j * 129 + i4 * 4 + 1],
                           fc_w[j * 129 + i4 * 4 + 2], fc_w[j * 129 + i4 * 4 + 3]);
    *(float4*)&ws[OFF_FCP + x * 4] = v; return;
  }
  x -= 4096;
  if (x < 4096) {                      // fc1P
    int i4 = x >> 7, j = x & 127;
    float4 v = make_float4(fc1_w[j * 128 + i4 * 4 + 0], fc1_w[j * 128 + i4 * 4 + 1],
                           fc1_w[j * 128 + i4 * 4 + 2], fc1_w[j * 128 + i4 * 4 + 3]);
    *(float4*)&ws[OFF_FC1P + x * 4] = v; return;
  }
  x -= 4096;
  if (x < 4096) {                      // mwP
    int i4 = x >> 7, j = x & 127;
    float4 v = make_float4(mw_w[j * 128 + i4 * 4 + 0], mw_w[j * 128 + i4 * 4 + 1],
                           mw_w[j * 128 + i4 * 4 + 2], mw_w[j * 128 + i4 * 4 + 3]);
    *(float4*)&ws[OFF_MWP + x * 4] = v; return;
  }
  x -= 4096;
  if (x < 4096) {                      // mvP
    int i4 = x >> 7, j = x & 127;
    float4 v = make_float4(mv_w[j * 128 + i4 * 4 + 0], mv_w[j * 128 + i4 * 4 + 1],
                           mv_w[j * 128 + i4 * 4 + 2], mv_w[j * 128 + i4 * 4 + 3]);
    *(float4*)&ws[OFF_MVP + x * 4] = v; return;
  }
  x -= 4096;
  if (x < 4096) {                      // FP : F[i2][j] = sum_d mfc[d][i2]*pk[d][j]
    int i4 = x >> 7, j = x & 127;
    float a[4] = {0.f, 0.f, 0.f, 0.f};
    for (int d = 0; d < 128; ++d) {
      float p = pk_w[d * 128 + j];
      a[0] = fmaf(mfc_w[d * 128 + i4 * 4 + 0], p, a[0]);
      a[1] = fmaf(mfc_w[d * 128 + i4 * 4 + 1], p, a[1]);
      a[2] = fmaf(mfc_w[d * 128 + i4 * 4 + 2], p, a[2]);
      a[3] = fmaf(mfc_w[d * 128 + i4 * 4 + 3], p, a[3]);
    }
    *(float4*)&ws[OFF_FP + x * 4] = make_float4(a[0], a[1], a[2], a[3]); return;
  }
  x -= 4096;
  if (x < 4096) {                      // mkP
    int hk = x >> 7, j = x & 127;
    int h = hk >> 2, k4 = hk & 3;
    float4 v = make_float4(mk_w[(h * 16 + k4 * 4 + 0) * 128 + j],
                           mk_w[(h * 16 + k4 * 4 + 1) * 128 + j],
                           mk_w[(h * 16 + k4 * 4 + 2) * 128 + j],
                           mk_w[(h * 16 + k4 * 4 + 3) * 128 + j]);
    *(float4*)&ws[OFF_MKP + x * 4] = v; return;
  }
  x -= 4096;
  if (x < 128) ws[OFF_FCC + x] = fc_w[x * 129 + 128];   // fc cap column
}

__global__ __launch_bounds__(512, 4) void decoder_loop(
    const float* __restrict__ enc, const float* __restrict__ pool,
    const float* __restrict__ capcity, const float* __restrict__ demand,
    const float* __restrict__ ws, float* __restrict__ d_out) {
  const float4* fcP  = (const float4*)(ws + OFF_FCP);
  const float4* fc1P = (const float4*)(ws + OFF_FC1P);
  const float4* mwP  = (const float4*)(ws + OFF_MWP);
  const float4* mvP  = (const float4*)(ws + OFF_MVP);
  const float4* FP   = (const float4*)(ws + OFF_FP);
  const float4* mkP  = (const float4*)(ws + OFF_MKP);

  __shared__ BS S;

  const int tl  = threadIdx.x;        // 0..511
  const int j   = tl & 127;
  const int qr  = tl >> 7;            // 0..3 (wave pair), wave-uniform
  const int myb = blockIdx.x;
  const float NEG_INF = -__builtin_inff();
  const float cap0 = capcity[0];

  // ---- stage enc slice into LDS ----
  {
    const float* src = enc + (size_t)myb * NNODE * DIM;
    for (int x = tl; x < NNODE * 32; x += 512) {
      int n = x >> 5, c = x & 31;
      *(float4*)&EL(n, c * 4) = *(const float4*)(src + (size_t)n * DIM + c * 4);
    }
  }
  __syncthreads();

  // ---- init carry ----
  if (tl < 128) S.pl[0][tl] = pool[(size_t)myb * DIM + tl];
  if (tl < NNODE) S.dem[tl] = demand[(size_t)myb * NNODE + tl];
  if (tl == 0) { S.cap = capcity[myb]; S.lp = 0.f; S.idx = 0; }
  __syncthreads();
  if (tl < NNODE) {
    float v1 = (tl == 0) ? 1.f : 0.f;
    S.mask1[tl] = v1;
    S.mask[tl] = (S.dem[tl] > S.cap) ? 1.f : v1;
  }
  __syncthreads();
  if (tl < 64) {
    bool ok = (tl == 0) || (S.mask[tl] > 0.5f);
    if (tl + 64 < NNODE) ok = ok && (S.mask[tl + 64] > 0.5f);
    bool alld = __all(ok);
    if (alld && tl == 0) S.mask[0] = 0.f;
  }
  __syncthreads();

  for (int step = 0; step < NSTEP; ++step) {
    const float capR = S.cap;
    const int   cidx = S.idx;
    const int   pp   = step & 1;

    // PH1: qr0 (SIMDs 0,1): fc from enc[cidx]; qr1 (SIMDs 2,3): fc1
    // from pl[pp] -> pl[pp^1]. Chains bit-exact vs R14.
    if (qr == 0) {
      const float4* x4 = (const float4*)&S.enc[cidx * ENCP];
      float A = 0.f;
      #pragma unroll 8
      for (int t = 0; t < 32; ++t) {
        float4 v = x4[t];
        float4 wv = fcP[t * 128 + j];
        A = fmaf(v.x, wv.x, A); A = fmaf(v.y, wv.y, A);
        A = fmaf(v.z, wv.z, A); A = fmaf(v.w, wv.w, A);
      }
      A = fmaf(capR, ws[OFF_FCC + j], A);
      S.dec[j] = A;
    } else if (qr == 1) {
      const float4* x4 = (const float4*)&S.pl[pp][0];
      float A = 0.f;
      #pragma unroll 8
      for (int t = 0; t < 32; ++t) {
        float4 v = x4[t];
        float4 wv = fc1P[t * 128 + j];
        A = fmaf(v.x, wv.x, A); A = fmaf(v.y, wv.y, A);
        A = fmaf(v.z, wv.z, A); A = fmaf(v.w, wv.w, A);
      }
      S.pl[pp ^ 1][j] = A;
    }
    __syncthreads();

    // PH2: qr0: Q. One full chain/thread; (dec+pl) inline. Bit-exact.
    if (qr == 0) {
      const float4* d4 = (const float4*)&S.dec[0];
      const float4* p4 = (const float4*)&S.pl[pp ^ 1][0];
      float B = 0.f;
      #pragma unroll 8
      for (int t = 0; t < 32; ++t) {
        float4 a = d4[t], p = p4[t];
        float4 wv = mwP[t * 128 + j];
        B = fmaf(a.x + p.x, wv.x, B); B = fmaf(a.y + p.y, wv.y, B);
        B = fmaf(a.z + p.z, wv.z, B); B = fmaf(a.w + p.w, wv.w, B);
      }
      S.q[j] = B;
    }
    __syncthreads();

    // PH2b: thread (qr, j) -> heads {2*qr, 2*qr+1}. Chains identical.
    {
      const float4* q4 = (const float4*)&S.q[0];
      #pragma unroll
      for (int hh = 0; hh < 2; ++hh) {
        int h = qr * 2 + hh;
        const float4* mp = mkP + (h * 4) * 128 + j;
        float4 M0 = mp[0], M1 = mp[128], M2 = mp[256], M3 = mp[384];
        float4 qa = q4[h * 4], qb = q4[h * 4 + 1], qc = q4[h * 4 + 2], qd4 = q4[h * 4 + 3];
        float acc = 0.f;
        acc = fmaf(qa.x, M0.x, acc); acc = fmaf(qa.y, M0.y, acc);
        acc = fmaf(qa.z, M0.z, acc); acc = fmaf(qa.w, M0.w, acc);
        acc = fmaf(qb.x, M1.x, acc); acc = fmaf(qb.y, M1.y, acc);
        acc = fmaf(qb.z, M1.z, acc); acc = fmaf(qb.w, M1.w, acc);
        acc = fmaf(qc.x, M2.x, acc); acc = fmaf(qc.y, M2.y, acc);
        acc = fmaf(qc.z, M2.z, acc); acc = fmaf(qc.w, M2.w, acc);
        acc = fmaf(qd4.x, M3.x, acc); acc = fmaf(qd4.y, M3.y, acc);
        acc = fmaf(qd4.z, M3.z, acc); acc = fmaf(qd4.w, M3.w, acc);
        QK(h, j) = acc;
      }
    }
    __syncthreads();

    // PH3: ALL 8 waves. Thread = (h = tl&7, nb = tl>>3); owns {nb, nb+64}.
    // Per-(h,n) chain: i4 ascending, x->y->z->w, single acc — bit-exact.
    {
      int h = tl & 7, nb = tl >> 3;        // h 0..7, nb 0..63
      int n1 = nb + 64;
      bool has1 = (n1 < NNODE);
      float a0 = 0.f, a1 = 0.f;
      #pragma unroll 4
      for (int i4 = 0; i4 < 32; ++i4) {
        float4 qv = *(const float4*)&QK(h, i4 * 4);
        float4 e0 = *(const float4*)&EL(nb, i4 * 4);
        a0 = fmaf(e0.x, qv.x, a0); a0 = fmaf(e0.y, qv.y, a0);
        a0 = fmaf(e0.z, qv.z, a0); a0 = fmaf(e0.w, qv.w, a0);
        if (has1) {
          float4 e1 = *(const float4*)&EL(n1, i4 * 4);
          a1 = fmaf(e1.x, qv.x, a1); a1 = fmaf(e1.y, qv.y, a1);
          a1 = fmaf(e1.z, qv.z, a1); a1 = fmaf(e1.w, qv.w, a1);
        }
      }
      {
        float mk0 = S.mask[nb];
        CMP(h, nb) = (mk0 > 0.5f) ? NEG_INF : 0.25f * a0;
      }
      if (has1) {
        float mk1 = S.mask[n1];
        CMP(h, n1) = (mk1 > 0.5f) ? NEG_INF : 0.25f * a1;
      }
    }
    __syncthreads();

    // PH4: softmax; 8 waves = 8 heads. Ladder identical per head.
    {
      int h = tl >> 6, lane = tl & 63;
      float v0 = CMP(h, lane);
      float v1 = (lane < NNODE - 64) ? CMP(h, lane + 64) : NEG_INF;
      float m = fmaxf(v0, v1);
      #pragma unroll
      for (int o = 32; o > 0; o >>= 1) m = fmaxf(m, __shfl_xor(m, o, 64));
      float e0 = expf(v0 - m);
      float e1 = (lane < NNODE - 64) ? expf(v1 - m) : 0.f;
      float ss = e0 + e1;
      #pragma unroll
      for (int o = 32; o > 0; o >>= 1) ss += __shfl_xor(ss, o, 64);
      SC(lane, h) = e0 / ss;
      if (lane < NNODE - 64) SC(lane + 64, h) = e1 / ss;
    }
    __syncthreads();

    // PH5: ALL 8 waves. Thread = (h = tl>>6, j2 = tl&63): 1 head, 2 dims.
    // Chain per (h,dim): n ascending — bit-exact.
    {
      int j2 = tl & 63, h = tl >> 6;
      float a00 = 0.f, a01 = 0.f;
      #pragma unroll 4
      for (int n = 0; n < NNODE; ++n) {
        float s   = SC(n, h);
        float2 ev = *(const float2*)&EL(n, j2 * 2);
        a00 = fmaf(s, ev.x, a00); a01 = fmaf(s, ev.y, a01);
      }
      *(float2*)&ZR(h, j2 * 2) = make_float2(a00, a01);
    }
    __syncthreads();

    // PH5b: qr1 (SIMDs 2,3): attn. One full chain/thread. Bit-exact.
    if (qr == 1) {
      int h = j >> 4;
      float C = 0.f;
      #pragma unroll 8
      for (int t = 0; t < 32; ++t) {
        float4 z = *(const float4*)&ZR(h, t * 4);
        float4 wv = mvP[t * 128 + j];
        C = fmaf(z.x, wv.x, C); C = fmaf(z.y, wv.y, C);
        C = fmaf(z.z, wv.z, C); C = fmaf(z.w, wv.w, C);
      }
      S.attn[j] = C;
    }
    __syncthreads();

    // PH6: qr0 (SIMDs 0,1): op. One full chain/thread. Bit-exact.
    if (qr == 0) {
      const float4* x4 = (const float4*)&S.attn[0];
      float D = 0.f;
      #pragma unroll 8
      for (int t = 0; t < 32; ++t) {
        float4 v = x4[t];
        float4 wv = FP[t * 128 + j];
        D = fmaf(v.x, wv.x, D); D = fmaf(v.y, wv.y, D);
        D = fmaf(v.z, wv.z, D); D = fmaf(v.w, wv.w, D);
      }
      S.op[j] = D;
    }
    __syncthreads();

    // PH7: ALL 8 waves. Thread = (qd = tl&3, n = tl>>2): 1 node.
    // Chain per (n,qd) identical.
    {
      int qd = tl & 3, n = tl >> 2;    // n 0..127
      if (n < NNODE) {
        float acc = 0.f;
        #pragma unroll
        for (int i4 = 0; i4 < 8; ++i4) {
          float4 ov = *(const float4*)&S.op[qd * 32 + i4 * 4];
          float4 e4 = *(const float4*)&EL(n, qd * 32 + i4 * 4);
          acc = fmaf(e4.x, ov.x, acc);
          acc = fmaf(e4.y, ov.y, acc);
          acc = fmaf(e4.z, ov.z, acc);
          acc = fmaf(e4.w, ov.w, acc);
        }
        SRED(n, qd) = acc;
      }
    }
    __syncthreads();

    // PH8 merged tail: logits, argmax, logsumexp, state, mask update (wave 0).
    if (tl < 64) {
      int lane = tl;
      float4 r0 = *(const float4*)&SRED(lane, 0);
      float tot0 = (r0.x + r0.y) + (r0.z + r0.w);
      float x0 = tanhf(tot0 * NORM_PROB) * 10.f;
      float v0 = (S.mask[lane] > 0.5f) ? NEG_INF : x0;
      float v1 = NEG_INF;
      if (lane < NNODE - 64) {
        float4 r1 = *(const float4*)&SRED(lane + 64, 0);
        float tot1 = (r1.x + r1.y) + (r1.z + r1.w);
        float x1 = tanhf(tot1 * NORM_PROB) * 10.f;
        v1 = (S.mask[lane + 64] > 0.5f) ? NEG_INF : x1;
      }
      float bv; int bi;
      if (v1 > v0) { bv = v1; bi = lane + 64; } else { bv = v0; bi = lane; }
      #pragma unroll
      for (int o = 32; o > 0; o >>= 1) {
        float ov = __shfl_xor(bv, o, 64);
        int   oi = __shfl_xor(bi, o, 64);
        if (ov > bv || (ov == bv && oi < bi)) { bv = ov; bi = oi; }
      }
      float e0 = expf(v0 - bv);
      float e1 = (lane < NNODE - 64) ? expf(v1 - bv) : 0.f;
      float ss = e0 + e1;
      #pragma unroll
      for (int o = 32; o > 0; o >>= 1) ss += __shfl_xor(ss, o, 64);
      int c = 0;
      if (lane >= 1 && S.mask1[lane] > 0.5f) c++;
      if (lane + 64 < NNODE && S.mask1[lane + 64] > 0.5f) c++;
      #pragma unroll
      for (int o = 32; o > 0; o >>= 1) c += __shfl_xor(c, o, 64);
      float newcap = (bi < 1) ? cap0 : (S.cap - S.dem[bi]);
      if (lane == 0) {
        if (c < NNODE - 1) S.lp += -logf(ss);
        d_out[(size_t)myb * NSTEP + step] = (float)bi;
        S.cap = newcap;
        S.idx = bi;
      }
      float m1a;
      if (lane == 0) m1a = (bi < 1) ? 1.f : 0.f;
      else           m1a = (lane == bi) ? 1.f : S.mask1[lane];
      float ma = (S.dem[lane] > newcap) ? 1.f : m1a;
      float m1b = 0.f, mb = 1.f;
      if (lane + 64 < NNODE) {
        m1b = (lane + 64 == bi) ? 1.f : S.mask1[lane + 64];
        mb  = (S.dem[lane + 64] > newcap) ? 1.f : m1b;
      }
      bool ok = (lane == 0) || (ma > 0.5f);
      if (lane + 64 < NNODE) ok = ok && (mb > 0.5f);
      bool alld = __all(ok);
      if (alld && lane == 0) ma = 0.f;
      S.mask1[lane] = m1a;
      S.mask[lane]  = ma;
      if (lane + 64 < NNODE) { S.mask1[lane + 64] = m1b; S.mask[lane + 64] = mb; }
    }
    __syncthreads();
  }

  if (tl == 0) d_out[(size_t)BTOT * NSTEP + myb] = S.lp;
}

extern "C" void kernel_launch(void* const* d_in, const int* in_sizes, int n_in,
                              void* d_out, int out_size, void* d_ws, size_t ws_size,
                              hipStream_t stream) {
  const float* enc   = (const float*)d_in[0];
  const float* pool  = (const float*)d_in[1];
  const float* cap   = (const float*)d_in[2];
  const float* dem   = (const float*)d_in[3];
  const float* fc_w  = (const float*)d_in[7];
  const float* fc1_w = (const float*)d_in[8];
  const float* pk_w  = (const float*)d_in[9];
  const float* mw_w  = (const float*)d_in[10];
  const float* mk_w  = (const float*)d_in[11];
  const float* mv_w  = (const float*)d_in[12];
  const float* mfc_w = (const float*)d_in[13];
  float* out = (float*)d_out;
  float* ws  = (float*)d_ws;

  prep_weights<<<97, 256, 0, stream>>>(fc_w, fc1_w, mw_w, mv_w, mfc_w, pk_w, mk_w, ws);
  decoder_loop<<<BTOT, 512, 0, stream>>>(enc, pool, cap, dem, ws, out);
}

// Round 13
// 9497.372 us; speedup vs baseline: 1.4951x; 1.4951x over previous
//
#include <hip/hip_runtime.h>

#define NNODE 101
#define DIM   128
#define NHEAD 8
#define NSTEP 150
#define BTOT  2048
#define ENCP  132          // padded enc row stride in LDS

// packed-weight ws layout (floats)
#define OFF_FCP   0
#define OFF_FC1P  16384
#define OFF_MWP   32768
#define OFF_MVP   49152
#define OFF_FP    65536
#define OFF_MKP   81920
#define OFF_FCC   98304
#define NORM_PROB 0.08838834764831845f

// R17 (resubmit — R12 bench was GPUAcquisitionTimeout, kernel never ran):
// R16's 512-thr regressed (VGPR 64 -> matvec ILP collapse, VALU 38->23).
// Back to the verified R14 chassis (256 thr / 1 elem / 2 blocks/CU, 9424 us)
// with bit-exact barrier elision:
//  (a) pl ping-pong (verified correct in R16) — kills PH1's internal barrier;
//  (b) PH3 remapped WAVE-LOCAL: wave w owns heads {2w,2w+1}; lane l: h=2w+(l>>5),
//      n0=l&31, nodes {n0,n0+32,n0+64,n0+96}. Per-(h,n) chain identical
//      (i4 ascending, x->y->z->w, single acc) -> bit-exact;
//  (c) PH3->PH4->PH5 now wave-local chains (PH4 wave w reads CMP rows its own
//      wave wrote; PH5 already wave-local in R14) -> the two barriers between
//      them become s_waitcnt lgkmcnt(0) fences (wave-lockstep LDS ordering).
// Barriers/step: 11 -> 8, and waves slip independently through PH3/4/5.
struct __align__(16) BS {
  float enc[NNODE * ENCP];              // 53,328 B
  float pl[2][DIM];                     // ping-pong: step s reads [s&1], writes [s&1^1]
  float dec[DIM], q[DIM], attn[DIM], op[DIM];
  float U[1888];                        // QK/ZR: h*132+i ; CMP: 1056+h*104+n
  float sc[1212];                       // SC: n*12+h ; SRED: n*12+k
  float mask[NNODE], mask1[NNODE], dem[NNODE];
  float cap, lp;
  int   idx;
};                                      // ~70.0 KB -> 2 blocks/CU

#define EL(n,i)     S.enc[(n)*ENCP + (i)]
#define QK(h,i)     S.U[(h)*132 + (i)]
#define ZR(h,i)     S.U[(h)*132 + (i)]
#define CMP(h,n)    S.U[1056 + (h)*104 + (n)]
#define SC(n,h)     S.sc[(n)*12 + (h)]
#define SRED(n,k)   S.sc[(n)*12 + (k)]

// wave-local LDS fence: orders this wave's ds_writes before its ds_reads
#define WAVE_FENCE() asm volatile("s_waitcnt lgkmcnt(0)" ::: "memory")

// Pack all weights as float4 panels: P[i4*128 + j] = {wT[i4*4+0][j], .., wT[i4*4+3][j]}
__global__ void prep_weights(const float* __restrict__ fc_w,
                             const float* __restrict__ fc1_w,
                             const float* __restrict__ mw_w,
                             const float* __restrict__ mv_w,
                             const float* __restrict__ mfc_w,
                             const float* __restrict__ pk_w,
                             const float* __restrict__ mk_w,
                             float* __restrict__ ws) {
  int x = blockIdx.x * 256 + threadIdx.x;
  if (x < 4096) {                      // fcP
    int i4 = x >> 7, j = x & 127;
    float4 v = make_float4(fc_w[j * 129 + i4 * 4 + 0], fc_w[j * 129 + i4 * 4 + 1],
                           fc_w[j * 129 + i4 * 4 + 2], fc_w[j * 129 + i4 * 4 + 3]);
    *(float4*)&ws[OFF_FCP + x * 4] = v; return;
  }
  x -= 4096;
  if (x < 4096) {                      // fc1P
    int i4 = x >> 7, j = x & 127;
    float4 v = make_float4(fc1_w[j * 128 + i4 * 4 + 0], fc1_w[j * 128 + i4 * 4 + 1],
                           fc1_w[j * 128 + i4 * 4 + 2], fc1_w[j * 128 + i4 * 4 + 3]);
    *(float4*)&ws[OFF_FC1P + x * 4] = v; return;
  }
  x -= 4096;
  if (x < 4096) {                      // mwP
    int i4 = x >> 7, j = x & 127;
    float4 v = make_float4(mw_w[j * 128 + i4 * 4 + 0], mw_w[j * 128 + i4 * 4 + 1],
                           mw_w[j * 128 + i4 * 4 + 2], mw_w[j * 128 + i4 * 4 + 3]);
    *(float4*)&ws[OFF_MWP + x * 4] = v; return;
  }
  x -= 4096;
  if (x < 4096) {                      // mvP
    int i4 = x >> 7, j = x & 127;
    float4 v = make_float4(mv_w[j * 128 + i4 * 4 + 0], mv_w[j * 128 + i4 * 4 + 1],
                           mv_w[j * 128 + i4 * 4 + 2], mv_w[j * 128 + i4 * 4 + 3]);
    *(float4*)&ws[OFF_MVP + x * 4] = v; return;
  }
  x -= 4096;
  if (x < 4096) {                      // FP : F[i2][j] = sum_d mfc[d][i2]*pk[d][j]
    int i4 = x >> 7, j = x & 127;
    float a[4] = {0.f, 0.f, 0.f, 0.f};
    for (int d = 0; d < 128; ++d) {
      float p = pk_w[d * 128 + j];
      a[0] = fmaf(mfc_w[d * 128 + i4 * 4 + 0], p, a[0]);
      a[1] = fmaf(mfc_w[d * 128 + i4 * 4 + 1], p, a[1]);
      a[2] = fmaf(mfc_w[d * 128 + i4 * 4 + 2], p, a[2]);
      a[3] = fmaf(mfc_w[d * 128 + i4 * 4 + 3], p, a[3]);
    }
    *(float4*)&ws[OFF_FP + x * 4] = make_float4(a[0], a[1], a[2], a[3]); return;
  }
  x -= 4096;
  if (x < 4096) {                      // mkP
    int hk = x >> 7, j = x & 127;
    int h = hk >> 2, k4 = hk & 3;
    float4 v = make_float4(mk_w[(h * 16 + k4 * 4 + 0) * 128 + j],
                           mk_w[(h * 16 + k4 * 4 + 1) * 128 + j],
                           mk_w[(h * 16 + k4 * 4 + 2) * 128 + j],
                           mk_w[(h * 16 + k4 * 4 + 3) * 128 + j]);
    *(float4*)&ws[OFF_MKP + x * 4] = v; return;
  }
  x -= 4096;
  if (x < 128) ws[OFF_FCC + x] = fc_w[x * 129 + 128];   // fc cap column
}

__global__ __launch_bounds__(256, 2) void decoder_loop(
    const float* __restrict__ enc, const float* __restrict__ pool,
    const float* __restrict__ capcity, const float* __restrict__ demand,
    const float* __restrict__ ws, float* __restrict__ d_out) {
  const float4* fcP  = (const float4*)(ws + OFF_FCP);
  const float4* fc1P = (const float4*)(ws + OFF_FC1P);
  const float4* mwP  = (const float4*)(ws + OFF_MWP);
  const float4* mvP  = (const float4*)(ws + OFF_MVP);
  const float4* FP   = (const float4*)(ws + OFF_FP);
  const float4* mkP  = (const float4*)(ws + OFF_MKP);

  __shared__ BS S;

  const int tl   = threadIdx.x;       // 0..255
  const int j    = tl & 127;
  const int half = tl >> 7;           // 0..1, wave-pair uniform
  const int myb  = blockIdx.x;
  const float NEG_INF = -__builtin_inff();
  const float cap0 = capcity[0];

  // ---- stage enc slice into LDS ----
  {
    const float* src = enc + (size_t)myb * NNODE * DIM;
    for (int x = tl; x < NNODE * 32; x += 256) {
      int n = x >> 5, c = x & 31;
      *(float4*)&EL(n, c * 4) = *(const float4*)(src + (size_t)n * DIM + c * 4);
    }
  }
  __syncthreads();

  // ---- init carry ----
  if (tl < 128) S.pl[0][tl] = pool[(size_t)myb * DIM + tl];
  if (tl < NNODE) S.dem[tl] = demand[(size_t)myb * NNODE + tl];
  if (tl == 0) { S.cap = capcity[myb]; S.lp = 0.f; S.idx = 0; }
  __syncthreads();
  if (tl < NNODE) {
    float v1 = (tl == 0) ? 1.f : 0.f;
    S.mask1[tl] = v1;
    S.mask[tl] = (S.dem[tl] > S.cap) ? 1.f : v1;
  }
  __syncthreads();
  if (tl < 64) {
    bool ok = (tl == 0) || (S.mask[tl] > 0.5f);
    if (tl + 64 < NNODE) ok = ok && (S.mask[tl + 64] > 0.5f);
    bool alld = __all(ok);
    if (alld && tl == 0) S.mask[0] = 0.f;
  }
  __syncthreads();

  for (int step = 0; step < NSTEP; ++step) {
    const float capR = S.cap;
    const int   cidx = S.idx;
    const int   pp   = step & 1;

    // PH1: half0: fc from enc[cidx] -> dec; half1: fc1 from pl[pp] -> pl[pp^1].
    // Ping-pong: no internal barrier. Chains bit-exact vs R14.
    {
      const float4* x4 = (half == 0) ? (const float4*)&S.enc[cidx * ENCP]
                                     : (const float4*)&S.pl[pp][0];
      const float4* wP = (half == 0) ? fcP : fc1P;
      float A = 0.f;
      #pragma unroll 8
      for (int t = 0; t < 32; ++t) {
        float4 v = x4[t];
        float4 wv = wP[t * 128 + j];
        A = fmaf(v.x, wv.x, A); A = fmaf(v.y, wv.y, A);
        A = fmaf(v.z, wv.z, A); A = fmaf(v.w, wv.w, A);
      }
      if (half == 0) A = fmaf(capR, ws[OFF_FCC + j], A);
      if (half == 0) S.dec[j] = A;
      else           S.pl[pp ^ 1][j] = A;
    }
    __syncthreads();

    // PH2: half0: Q. One full chain/thread; (dec+pl) inline. Bit-exact.
    if (half == 0) {
      const float4* d4 = (const float4*)&S.dec[0];
      const float4* p4 = (const float4*)&S.pl[pp ^ 1][0];
      float B = 0.f;
      #pragma unroll 8
      for (int t = 0; t < 32; ++t) {
        float4 a = d4[t], p = p4[t];
        float4 wv = mwP[t * 128 + j];
        B = fmaf(a.x + p.x, wv.x, B); B = fmaf(a.y + p.y, wv.y, B);
        B = fmaf(a.z + p.z, wv.z, B); B = fmaf(a.w + p.w, wv.w, B);
      }
      S.q[j] = B;
    }
    __syncthreads();

    // PH2b: thread (half, j) -> heads {4*half .. 4*half+3}. Chains identical.
    {
      const float4* q4 = (const float4*)&S.q[0];
      #pragma unroll
      for (int hh = 0; hh < 4; ++hh) {
        int h = half * 4 + hh;
        const float4* mp = mkP + (h * 4) * 128 + j;
        float4 M0 = mp[0], M1 = mp[128], M2 = mp[256], M3 = mp[384];
        float4 qa = q4[h * 4], qb = q4[h * 4 + 1], qc = q4[h * 4 + 2], qd4 = q4[h * 4 + 3];
        float acc = 0.f;
        acc = fmaf(qa.x, M0.x, acc); acc = fmaf(qa.y, M0.y, acc);
        acc = fmaf(qa.z, M0.z, acc); acc = fmaf(qa.w, M0.w, acc);
        acc = fmaf(qb.x, M1.x, acc); acc = fmaf(qb.y, M1.y, acc);
        acc = fmaf(qb.z, M1.z, acc); acc = fmaf(qb.w, M1.w, acc);
        acc = fmaf(qc.x, M2.x, acc); acc = fmaf(qc.y, M2.y, acc);
        acc = fmaf(qc.z, M2.z, acc); acc = fmaf(qc.w, M2.w, acc);
        acc = fmaf(qd4.x, M3.x, acc); acc = fmaf(qd4.y, M3.y, acc);
        acc = fmaf(qd4.z, M3.z, acc); acc = fmaf(qd4.w, M3.w, acc);
        QK(h, j) = acc;
      }
    }
    __syncthreads();

    // ===== fused PH3 -> PH4 -> PH5: wave-local, no barriers inside =====

    // PH3: wave w owns heads {2w, 2w+1}. Lane l: h = 2w + (l>>5), n0 = l&31,
    // nodes {n0, n0+32, n0+64, n0+96}. Per-(h,n) chain: i4 ascending,
    // x->y->z->w, single acc, 0.25f scale — bit-exact vs R14.
    {
      int w = tl >> 6, l = tl & 63;
      int h = 2 * w + (l >> 5), n0 = l & 31;
      bool has3 = (n0 + 96 < NNODE);
      float a0 = 0.f, a1 = 0.f, a2 = 0.f, a3 = 0.f;
      #pragma unroll 4
      for (int i4 = 0; i4 < 32; ++i4) {
        float4 qv = *(const float4*)&QK(h, i4 * 4);
        float4 e0 = *(const float4*)&EL(n0,      i4 * 4);
        float4 e1 = *(const float4*)&EL(n0 + 32, i4 * 4);
        float4 e2 = *(const float4*)&EL(n0 + 64, i4 * 4);
        a0 = fmaf(e0.x, qv.x, a0); a0 = fmaf(e0.y, qv.y, a0);
        a0 = fmaf(e0.z, qv.z, a0); a0 = fmaf(e0.w, qv.w, a0);
        a1 = fmaf(e1.x, qv.x, a1); a1 = fmaf(e1.y, qv.y, a1);
        a1 = fmaf(e1.z, qv.z, a1); a1 = fmaf(e1.w, qv.w, a1);
        a2 = fmaf(e2.x, qv.x, a2); a2 = fmaf(e2.y, qv.y, a2);
        a2 = fmaf(e2.z, qv.z, a2); a2 = fmaf(e2.w, qv.w, a2);
        if (has3) {
          float4 e3 = *(const float4*)&EL(n0 + 96, i4 * 4);
          a3 = fmaf(e3.x, qv.x, a3); a3 = fmaf(e3.y, qv.y, a3);
          a3 = fmaf(e3.z, qv.z, a3); a3 = fmaf(e3.w, qv.w, a3);
        }
      }
      float mk;
      mk = S.mask[n0];      CMP(h, n0)      = (mk > 0.5f) ? NEG_INF : 0.25f * a0;
      mk = S.mask[n0 + 32]; CMP(h, n0 + 32) = (mk > 0.5f) ? NEG_INF : 0.25f * a1;
      mk = S.mask[n0 + 64]; CMP(h, n0 + 64) = (mk > 0.5f) ? NEG_INF : 0.25f * a2;
      if (has3) {
        mk = S.mask[n0 + 96]; CMP(h, n0 + 96) = (mk > 0.5f) ? NEG_INF : 0.25f * a3;
      }
    }
    WAVE_FENCE();   // wave w's CMP writes -> its own PH4 reads

    // PH4: softmax; wave w = heads {2w, 2w+1} (reads only own wave's CMP rows).
    {
      int w = tl >> 6, lane = tl & 63;
      int hb = w * 2;
      #pragma unroll
      for (int hh = 0; hh < 2; ++hh) {
        int h = hb + hh;
        float v0 = CMP(h, lane);
        float v1 = (lane < NNODE - 64) ? CMP(h, lane + 64) : NEG_INF;
        float m = fmaxf(v0, v1);
        #pragma unroll
        for (int o = 32; o > 0; o >>= 1) m = fmaxf(m, __shfl_xor(m, o, 64));
        float e0 = expf(v0 - m);
        float e1 = (lane < NNODE - 64) ? expf(v1 - m) : 0.f;
        float ss = e0 + e1;
        #pragma unroll
        for (int o = 32; o > 0; o >>= 1) ss += __shfl_xor(ss, o, 64);
        SC(lane, h) = e0 / ss;
        if (lane < NNODE - 64) SC(lane + 64, h) = e1 / ss;
      }
    }
    WAVE_FENCE();   // wave w's SC writes -> its own PH5 reads

    // PH5: wave w = head pair {2w, 2w+1} (reads only own wave's SC columns).
    // Thread (w, j2 = tl&63): chain per (h,dim): n ascending — bit-exact.
    {
      int j2 = tl & 63, hp = tl >> 6, hb = hp * 2;
      float a00 = 0.f, a01 = 0.f, a10 = 0.f, a11 = 0.f;
      #pragma unroll 4
      for (int n = 0; n < NNODE; ++n) {
        float2 s  = *(const float2*)&SC(n, hb);
        float2 ev = *(const float2*)&EL(n, j2 * 2);
        a00 = fmaf(s.x, ev.x, a00); a01 = fmaf(s.x, ev.y, a01);
        a10 = fmaf(s.y, ev.x, a10); a11 = fmaf(s.y, ev.y, a11);
      }
      *(float2*)&ZR(hb + 0, j2 * 2) = make_float2(a00, a01);
      *(float2*)&ZR(hb + 1, j2 * 2) = make_float2(a10, a11);
    }
    __syncthreads();

    // PH5b: half1: attn. One full chain/thread. Bit-exact.
    if (half == 1) {
      int h = j >> 4;
      float C = 0.f;
      #pragma unroll 8
      for (int t = 0; t < 32; ++t) {
        float4 z = *(const float4*)&ZR(h, t * 4);
        float4 wv = mvP[t * 128 + j];
        C = fmaf(z.x, wv.x, C); C = fmaf(z.y, wv.y, C);
        C = fmaf(z.z, wv.z, C); C = fmaf(z.w, wv.w, C);
      }
      S.attn[j] = C;
    }
    __syncthreads();

    // PH6: half0: op. One full chain/thread. Bit-exact.
    if (half == 0) {
      const float4* x4 = (const float4*)&S.attn[0];
      float D = 0.f;
      #pragma unroll 8
      for (int t = 0; t < 32; ++t) {
        float4 v = x4[t];
        float4 wv = FP[t * 128 + j];
        D = fmaf(v.x, wv.x, D); D = fmaf(v.y, wv.y, D);
        D = fmaf(v.z, wv.z, D); D = fmaf(v.w, wv.w, D);
      }
      S.op[j] = D;
    }
    __syncthreads();

    // PH7: comp2 partials — all 4 waves (bit-exact mapping vs R14).
    {
      int qd = tl & 3, nq = tl >> 2;   // nq 0..63
      #pragma unroll
      for (int p = 0; p < 2; ++p) {
        int n = p * 64 + nq;
        if (n < NNODE) {
          float acc = 0.f;
          #pragma unroll
          for (int i4 = 0; i4 < 8; ++i4) {
            float4 ov = *(const float4*)&S.op[qd * 32 + i4 * 4];
            float4 e4 = *(const float4*)&EL(n, qd * 32 + i4 * 4);
            acc = fmaf(e4.x, ov.x, acc);
            acc = fmaf(e4.y, ov.y, acc);
            acc = fmaf(e4.z, ov.z, acc);
            acc = fmaf(e4.w, ov.w, acc);
          }
          SRED(n, qd) = acc;
        }
      }
    }
    __syncthreads();

    // PH8 merged tail: logits, argmax, logsumexp, state, mask update (wave 0).
    if (tl < 64) {
      int lane = tl;
      float4 r0 = *(const float4*)&SRED(lane, 0);
      float tot0 = (r0.x + r0.y) + (r0.z + r0.w);
      float x0 = tanhf(tot0 * NORM_PROB) * 10.f;
      float v0 = (S.mask[lane] > 0.5f) ? NEG_INF : x0;
      float v1 = NEG_INF;
      if (lane < NNODE - 64) {
        float4 r1 = *(const float4*)&SRED(lane + 64, 0);
        float tot1 = (r1.x + r1.y) + (r1.z + r1.w);
        float x1 = tanhf(tot1 * NORM_PROB) * 10.f;
        v1 = (S.mask[lane + 64] > 0.5f) ? NEG_INF : x1;
      }
      float bv; int bi;
      if (v1 > v0) { bv = v1; bi = lane + 64; } else { bv = v0; bi = lane; }
      #pragma unroll
      for (int o = 32; o > 0; o >>= 1) {
        float ov = __shfl_xor(bv, o, 64);
        int   oi = __shfl_xor(bi, o, 64);
        if (ov > bv || (ov == bv && oi < bi)) { bv = ov; bi = oi; }
      }
      float e0 = expf(v0 - bv);
      float e1 = (lane < NNODE - 64) ? expf(v1 - bv) : 0.f;
      float ss = e0 + e1;
      #pragma unroll
      for (int o = 32; o > 0; o >>= 1) ss += __shfl_xor(ss, o, 64);
      int c = 0;
      if (lane >= 1 && S.mask1[lane] > 0.5f) c++;
      if (lane + 64 < NNODE && S.mask1[lane + 64] > 0.5f) c++;
      #pragma unroll
      for (int o = 32; o > 0; o >>= 1) c += __shfl_xor(c, o, 64);
      float newcap = (bi < 1) ? cap0 : (S.cap - S.dem[bi]);
      if (lane == 0) {
        if (c < NNODE - 1) S.lp += -logf(ss);
        d_out[(size_t)myb * NSTEP + step] = (float)bi;
        S.cap = newcap;
        S.idx = bi;
      }
      float m1a;
      if (lane == 0) m1a = (bi < 1) ? 1.f : 0.f;
      else           m1a = (lane == bi) ? 1.f : S.mask1[lane];
      float ma = (S.dem[lane] > newcap) ? 1.f : m1a;
      float m1b = 0.f, mb = 1.f;
      if (lane + 64 < NNODE) {
        m1b = (lane + 64 == bi) ? 1.f : S.mask1[lane + 64];
        mb  = (S.dem[lane + 64] > newcap) ? 1.f : m1b;
      }
      bool ok = (lane == 0) || (ma > 0.5f);
      if (lane + 64 < NNODE) ok = ok && (mb > 0.5f);
      bool alld = __all(ok);
      if (alld && lane == 0) ma = 0.f;
      S.mask1[lane] = m1a;
      S.mask[lane]  = ma;
      if (lane + 64 < NNODE) { S.mask1[lane + 64] = m1b; S.mask[lane + 64] = mb; }
    }
    __syncthreads();
  }

  if (tl == 0) d_out[(size_t)BTOT * NSTEP + myb] = S.lp;
}

extern "C" void kernel_launch(void* const* d_in, const int* in_sizes, int n_in,
                              void* d_out, int out_size, void* d_ws, size_t ws_size,
                              hipStream_t stream) {
  const float* enc   = (const float*)d_in[0];
  const float* pool  = (const float*)d_in[1];
  const float* cap   = (const float*)d_in[2];
  const float* dem   = (const float*)d_in[3];
  const float* fc_w  = (const float*)d_in[7];
  const float* fc1_w = (const float*)d_in[8];
  const float* pk_w  = (const float*)d_in[9];
  const float* mw_w  = (const float*)d_in[10];
  const float* mk_w  = (const float*)d_in[11];
  const float* mv_w  = (const float*)d_in[12];
  const float* mfc_w = (const float*)d_in[13];
  float* out = (float*)d_out;
  float* ws  = (float*)d_ws;

  prep_weights<<<97, 256, 0, stream>>>(fc_w, fc1_w, mw_w, mv_w, mfc_w, pk_w, mk_w, ws);
  decoder_loop<<<BTOT, 256, 0, stream>>>(enc, pool, cap, dem, ws, out);
}